// Round 21
// baseline (4308.408 us; speedup 1.0000x reference)
//
#include <hip/hip_runtime.h>
#include <stdint.h>

#define L_ 4
#define B_ 2
#define T_ 1024
#define D_ 2048
#define HQ_ 16
#define HKV_ 4
#define DK_ 128
#define HID_ 5464
#define HIDP_ 5504
#define BT_ (B_*T_)
#define NQKV_ (HQ_*DK_ + 2*HKV_*DK_)   /* 3072 */
#define VOFF_ (HQ_*DK_ + HKV_*DK_)     /* 2560 */

typedef unsigned short u16;
typedef float f32x4 __attribute__((ext_vector_type(4)));
typedef __bf16 bf16x8 __attribute__((ext_vector_type(8)));

__device__ __forceinline__ u16 f2bs(float f) {
  unsigned u = __float_as_uint(f);
  u += 0x7fffu + ((u >> 16) & 1u);
  return (u16)(u >> 16);
}
__device__ __forceinline__ float bs2f(u16 s) {
  return __uint_as_float(((unsigned)s) << 16);
}

// async global->LDS, 16B per lane. LDS dest = first-lane value + lane*16.
__device__ __forceinline__ void async16(void* lds, const void* g) {
  __builtin_amdgcn_global_load_lds(
      (const __attribute__((address_space(1))) unsigned*)(uintptr_t)g,
      (__attribute__((address_space(3))) unsigned*)(unsigned)(uintptr_t)lds,
      16, 0, 0);
}

__device__ __forceinline__ f32x4 mfma16(bf16x8 a, bf16x8 b, f32x4 c) {
  return __builtin_amdgcn_mfma_f32_16x16x32_bf16(a, b, c, 0, 0, 0);
}

// Bijective XCD chunking (m204) + Triton-style GROUP block-order swizzle for L2 reuse.
__device__ __forceinline__ void remap_bid(int& bm, int& bn) {
  const int nbx = gridDim.x, nby = gridDim.y;
  const int nwg = nbx * nby;
  const int lin = blockIdx.y * nbx + blockIdx.x;
  const int q = nwg >> 3, r = nwg & 7;
  const int xcd = lin & 7, rest = lin >> 3;
  const int wgid = (xcd < r ? xcd * (q + 1) : r * (q + 1) + (xcd - r) * q) + rest;
  const int GROUP = 4;
  const int tpg = GROUP * nby;
  const int gid = wgid / tpg;
  const int first = gid * GROUP;
  const int size = (GROUP < nbx - first) ? GROUP : (nbx - first);
  const int rem = wgid - gid * tpg;
  bn = first + rem % size;
  bm = rem / size;
}

// ---------------------------------------------------------------- utility
__global__ void copy_f4_k(const float4* __restrict__ src, float4* __restrict__ dst, int n4) {
  int i = blockIdx.x * blockDim.x + threadIdx.x;
  if (i < n4) dst[i] = src[i];
}

__global__ void rope_tab_k(float* __restrict__ ct, float* __restrict__ st) {
  int idx = blockIdx.x * 256 + threadIdx.x;   // T_*64 total
  int t = idx >> 6, i = idx & 63;
  float inv = expf(-(float)i * (9.210340371976184f / 64.f));  // 10000^(-i/64)
  float fr = (float)t * inv;
  ct[idx] = cosf(fr);
  st[idx] = sinf(fr);
}

// transpose + fp32->(hi,lo) split: out[oi][oj] = in[oj][oi], zero-pad outside [inR][inC]
__global__ __launch_bounds__(256) void transpose_split_k(
    const float* __restrict__ in, u16* __restrict__ outh, u16* __restrict__ outl,
    int inR, int inC, int outC) {
  __shared__ float tile[64][65];
  const int oj0 = blockIdx.x * 64;   // out col = in row
  const int oi0 = blockIdx.y * 64;   // out row = in col
  #pragma unroll
  for (int rep = 0; rep < 16; ++rep) {
    int idx = rep * 256 + threadIdx.x;
    int a = idx >> 6, b = idx & 63;
    int ir = oj0 + a, ic = oi0 + b;
    tile[a][b] = (ir < inR && ic < inC) ? in[(size_t)ir * inC + ic] : 0.f;
  }
  __syncthreads();
  #pragma unroll
  for (int rep = 0; rep < 16; ++rep) {
    int idx = rep * 256 + threadIdx.x;
    int ii = idx >> 6, jj = idx & 63;
    float val = tile[jj][ii];
    u16 hh = f2bs(val);
    const size_t o = (size_t)(oi0 + ii) * outC + oj0 + jj;
    outh[o] = hh;
    outl[o] = f2bs(val - bs2f(hh));
  }
}

// v (strided inside fused qkv, fp32) -> split bf16 vt [B,HKV,DK,T]
__global__ __launch_bounds__(256) void transpose_v_split_k(const float* __restrict__ qkv,
    u16* __restrict__ vth, u16* __restrict__ vtl) {
  __shared__ float tile[64][65];
  const int bz = blockIdx.z;            // b*HKV + hkv
  const int b = bz >> 2, hkv = bz & 3;
  const int t0 = blockIdx.x * 64, d0 = blockIdx.y * 64;
  #pragma unroll
  for (int rep = 0; rep < 16; ++rep) {
    int idx = rep * 256 + threadIdx.x;
    int a = idx >> 6, c = idx & 63;
    tile[a][c] = qkv[(size_t)(b * T_ + t0 + a) * NQKV_ + VOFF_ + hkv * DK_ + d0 + c];
  }
  __syncthreads();
  #pragma unroll
  for (int rep = 0; rep < 16; ++rep) {
    int idx = rep * 256 + threadIdx.x;
    int aa = idx & 63, cc = idx >> 6;
    float val = tile[aa][cc];
    u16 hh = f2bs(val);
    const size_t o = ((size_t)bz * DK_ + d0 + cc) * T_ + t0 + aa;
    vth[o] = hh;
    vtl[o] = f2bs(val - bs2f(hh));
  }
}

// ---------------------------------------------------------------- rmsnorm fp32 -> fp32
__global__ __launch_bounds__(256) void rmsnorm_f(const float* x,
    const float* __restrict__ sc, float* out) {
  const int row = blockIdx.x;
  const float* xr = x + (size_t)row * D_;
  float ss = 0.f;
  #pragma unroll
  for (int it = 0; it < D_ / 1024; ++it) {
    int i = (it * 256 + threadIdx.x) * 4;
    float4 v = *(const float4*)(xr + i);
    ss += v.x * v.x + v.y * v.y + v.z * v.z + v.w * v.w;
  }
  #pragma unroll
  for (int o = 1; o < 64; o <<= 1) ss += __shfl_xor(ss, o);
  __shared__ float red[4];
  if ((threadIdx.x & 63) == 0) red[threadIdx.x >> 6] = ss;
  __syncthreads();
  float tot = red[0] + red[1] + red[2] + red[3];
  float r = rsqrtf(tot * (1.f / D_) + 1e-5f);
  float* orow = out + (size_t)row * D_;
  #pragma unroll
  for (int it = 0; it < D_ / 1024; ++it) {
    int i = (it * 256 + threadIdx.x) * 4;
    float4 v = *(const float4*)(xr + i);
    float4 s4 = *(const float4*)(sc + i);
    float4 o4;
    o4.x = v.x * s4.x * r; o4.y = v.y * s4.y * r;
    o4.z = v.z * s4.z * r; o4.w = v.w * s4.w * r;
    *(float4*)(orow + i) = o4;
  }
}

// ---------------------------------------------------------------- rmsnorm fp32 -> split bf16
__global__ __launch_bounds__(256) void rmsnorm_s(const float* x,
    const float* __restrict__ sc, u16* ohi, u16* olo) {
  const int row = blockIdx.x;
  const float* xr = x + (size_t)row * D_;
  float ss = 0.f;
  #pragma unroll
  for (int it = 0; it < D_ / 1024; ++it) {
    int i = (it * 256 + threadIdx.x) * 4;
    float4 v = *(const float4*)(xr + i);
    ss += v.x * v.x + v.y * v.y + v.z * v.z + v.w * v.w;
  }
  #pragma unroll
  for (int o = 1; o < 64; o <<= 1) ss += __shfl_xor(ss, o);
  __shared__ float red[4];
  if ((threadIdx.x & 63) == 0) red[threadIdx.x >> 6] = ss;
  __syncthreads();
  float tot = red[0] + red[1] + red[2] + red[3];
  float r = rsqrtf(tot * (1.f / D_) + 1e-5f);
  #pragma unroll
  for (int it = 0; it < D_ / 1024; ++it) {
    int i = (it * 256 + threadIdx.x) * 4;
    float4 v = *(const float4*)(xr + i);
    float4 s4 = *(const float4*)(sc + i);
    float o0 = v.x * s4.x * r, o1 = v.y * s4.y * r, o2 = v.z * s4.z * r, o3 = v.w * s4.w * r;
    u16 h0 = f2bs(o0), h1 = f2bs(o1), h2 = f2bs(o2), h3 = f2bs(o3);
    u16 l0 = f2bs(o0 - bs2f(h0)), l1 = f2bs(o1 - bs2f(h1));
    u16 l2 = f2bs(o2 - bs2f(h2)), l3 = f2bs(o3 - bs2f(h3));
    uint2 ph, pl;
    ph.x = (unsigned)h0 | ((unsigned)h1 << 16); ph.y = (unsigned)h2 | ((unsigned)h3 << 16);
    pl.x = (unsigned)l0 | ((unsigned)l1 << 16); pl.y = (unsigned)l2 | ((unsigned)l3 << 16);
    *(uint2*)(ohi + (size_t)row * D_ + i) = ph;
    *(uint2*)(olo + (size_t)row * D_ + i) = pl;
  }
}

// ---------------------------------------------------------------- SPLIT-bf16 MFMA GEMM
// BM=256 x BN=128 tile, 512 threads / 8 waves (4x2 of 64x64), BK=32,
// SINGLE 48KB LDS buffer -> 2 blocks/CU = 4 waves/SIMD (the proven sweet spot).
// vs R20 (32x64 waves): MFMA:ds_read ratio 3.0 (48 MFMA / 16 reads per wave) vs 2.0,
// 2x MFMA per barrier-pair, 25% less staged bytes per FLOP. acc[4][4]=64 VGPR +
// operands ~= 100 total, safely under the 128 cap of (512,4) (R19 spill lesson).
// Per-K-step drain (vmcnt(0)+syncthreads) hidden by the co-resident second block
// (m114/R15 mechanism). FFN grid 43x8=344 blocks <= 512 capacity (one round).
// C = (Ahi+Alo) x (Bhi+Blo)^T dropping lo*lo. A[M][K], Bt[N][K].
// Swizzle (rule 21): linear LDS dest, 64B rows, src chunk ^= (row>>1)&3, read same mask.
// Per-output accum chain identical (kt ascending, hh/hl/lh order) -> bitwise-same C.
// MODE 0: Cf = acc ; 1: Cf += acc ; 2: in-place gelu: r=gelu(Chi+Clo)*acc -> Chi/Clo ;
// MODE 3: split acc -> Chi/Clo.
template <int MODE>
__global__ __launch_bounds__(512, 4) void gemm_bts_k(
    const u16* __restrict__ Ahi, const u16* __restrict__ Alo,
    const u16* __restrict__ Bthi, const u16* __restrict__ Btlo,
    float* Cf, u16* Chi, u16* Clo, int N, int K) {
  __shared__ u16 smem[24576];                 // 48KB: Ah(16K)|Al(16K)|Bh(8K)|Bl(8K)
  const int tid = threadIdx.x, w = tid >> 6, lane = tid & 63;
  const int g = lane >> 4, r16 = lane & 15;
  int bm, bn;
  remap_bid(bm, bn);
  const int m0 = bm * 256, n0 = bn * 128;
  const int wr = w >> 1, wc = w & 1;          // 4 x 2 waves, each 64x64
  f32x4 acc[4][4] = {};
  const int nkt = K >> 5;

  char* Ash = (char*)smem;                    // 256 rows x 64B
  char* Asl = (char*)smem + 16384;
  char* Bsh = (char*)smem + 32768;            // 128 rows x 64B
  char* Bsl = (char*)smem + 40960;

  for (int kt = 0; kt < nkt; ++kt) {
    // stage tile kt: A 2x8KB rounds, B 1x8KB round (6 async16/thread)
    #pragma unroll
    for (int i = 0; i < 2; ++i) {
      const int p = i * 8192 + tid * 16;
      const int row = p >> 6;                                // 0..255
      const int sc = ((p >> 4) & 3) ^ ((row >> 1) & 3);
      const size_t ga = (size_t)(m0 + row) * K + (kt << 5) + sc * 8;
      async16(Ash + p, Ahi + ga);
      async16(Asl + p, Alo + ga);
    }
    {
      const int p = tid * 16;
      const int row = p >> 6;                                // 0..127
      const int sc = ((p >> 4) & 3) ^ ((row >> 1) & 3);
      const size_t gb = (size_t)(n0 + row) * K + (kt << 5) + sc * 8;
      async16(Bsh + p, Bthi + gb);
      async16(Bsl + p, Btlo + gb);
    }
    asm volatile("s_waitcnt vmcnt(0)" ::: "memory");
    __syncthreads();
    bf16x8 ah[4], al[4], bh[4], bl[4];
    #pragma unroll
    for (int m = 0; m < 4; ++m) {
      const int row = wr * 64 + m * 16 + r16;
      const int ch = g ^ ((row >> 1) & 3);
      const int off = row * 64 + ch * 16;
      ah[m] = *(const bf16x8*)(Ash + off);
      al[m] = *(const bf16x8*)(Asl + off);
    }
    #pragma unroll
    for (int n = 0; n < 4; ++n) {
      const int row = wc * 64 + n * 16 + r16;
      const int ch = g ^ ((row >> 1) & 3);
      const int off = row * 64 + ch * 16;
      bh[n] = *(const bf16x8*)(Bsh + off);
      bl[n] = *(const bf16x8*)(Bsl + off);
    }
    #pragma unroll
    for (int m = 0; m < 4; ++m)
      #pragma unroll
      for (int n = 0; n < 4; ++n) {
        acc[m][n] = mfma16(ah[m], bh[n], acc[m][n]);
        acc[m][n] = mfma16(ah[m], bl[n], acc[m][n]);
        acc[m][n] = mfma16(al[m], bh[n], acc[m][n]);
      }
    __syncthreads();   // ds_reads retired (compiler waitcnt) -> safe to restage
  }
  #pragma unroll
  for (int m = 0; m < 4; ++m) {
    const int rbase = m0 + wr * 64 + m * 16 + g * 4;
    #pragma unroll
    for (int n = 0; n < 4; ++n) {
      const int c = n0 + wc * 64 + n * 16 + r16;
      #pragma unroll
      for (int j = 0; j < 4; ++j) {
        const size_t idx = (size_t)(rbase + j) * N + c;
        const float v = acc[m][n][j];
        if constexpr (MODE == 0) {
          Cf[idx] = v;
        } else if constexpr (MODE == 1) {
          Cf[idx] += v;
        } else if constexpr (MODE == 2) {
          const float gv = bs2f(Chi[idx]) + bs2f(Clo[idx]);
          const float ge = 0.5f * gv * (1.f + erff(gv * 0.70710678118654752f));
          const float r = ge * v;
          const u16 rh = f2bs(r);
          Chi[idx] = rh;
          Clo[idx] = f2bs(r - bs2f(rh));
        } else {
          const u16 rh = f2bs(v);
          Chi[idx] = rh;
          Clo[idx] = f2bs(v - bs2f(rh));
        }
      }
    }
  }
}

// ---------------------------------------------------------------- fused rope + q/k split
__global__ __launch_bounds__(256) void rope_split_qkv_k(const float* __restrict__ qkv,
    const float* __restrict__ ct, const float* __restrict__ st,
    u16* __restrict__ qhi, u16* __restrict__ qlo,
    u16* __restrict__ khi, u16* __restrict__ klo) {
  const int row = blockIdx.x;          // b*T + t
  const int t = row & (T_ - 1);
  const float* src = qkv + (size_t)row * NQKV_;
  u16* qh = qhi + (size_t)row * (HQ_ * DK_);
  u16* ql = qlo + (size_t)row * (HQ_ * DK_);
  for (int idx = threadIdx.x; idx < HQ_ * 64; idx += 256) {
    int h = idx >> 6, i = idx & 63;
    float c = ct[t * 64 + i], s = st[t * 64 + i];
    float x1 = src[h * DK_ + i], x2 = src[h * DK_ + i + 64];
    float r1 = x1 * c - x2 * s;
    float r2 = x2 * c + x1 * s;
    u16 h1 = f2bs(r1), h2v = f2bs(r2);
    qh[h * DK_ + i]      = h1;  ql[h * DK_ + i]      = f2bs(r1 - bs2f(h1));
    qh[h * DK_ + i + 64] = h2v; ql[h * DK_ + i + 64] = f2bs(r2 - bs2f(h2v));
  }
  const float* srck = src + HQ_ * DK_;
  u16* kh = khi + (size_t)row * (HKV_ * DK_);
  u16* kl = klo + (size_t)row * (HKV_ * DK_);
  for (int idx = threadIdx.x; idx < HKV_ * 64; idx += 256) {
    int h = idx >> 6, i = idx & 63;
    float c = ct[t * 64 + i], s = st[t * 64 + i];
    float x1 = srck[h * DK_ + i], x2 = srck[h * DK_ + i + 64];
    float r1 = x1 * c - x2 * s;
    float r2 = x2 * c + x1 * s;
    u16 h1 = f2bs(r1), h2v = f2bs(r2);
    kh[h * DK_ + i]      = h1;  kl[h * DK_ + i]      = f2bs(r1 - bs2f(h1));
    kh[h * DK_ + i + 64] = h2v; kl[h * DK_ + i + 64] = f2bs(r2 - bs2f(h2v));
  }
}

// ---------------------------------------------------------------- SPLIT-bf16 MFMA flash attention
__global__ __launch_bounds__(256) void attn_s_k(
    const u16* __restrict__ Qh, const u16* __restrict__ Ql,
    const u16* __restrict__ Kh, const u16* __restrict__ Kl,
    const u16* __restrict__ VTh, const u16* __restrict__ VTl,
    u16* __restrict__ Ohi, u16* __restrict__ Olo, const int* __restrict__ candp) {
  __shared__ u16 sm[40960];                 // 80 KB
  char* Kth = (char*)sm;                    // 64 kv x 256B
  char* Ktl = (char*)sm + 16384;
  char* Vth = (char*)sm + 32768;            // 128 d x 128B
  char* Vtl = (char*)sm + 49152;
  const int b = blockIdx.z, hq = blockIdx.y, q0 = blockIdx.x * 64;
  const int hkv = hq >> 2;
  const int tid = threadIdx.x, w = tid >> 6, lane = tid & 63;
  const int g = lane >> 4, r16 = lane & 15;
  char* Pth = (char*)sm + 65536 + w * 2048;        // 4 waves x 2KB
  char* Ptl = (char*)sm + 65536 + 8192 + w * 2048; // 4 waves x 2KB (ends at 81920)
  const int CANDv = *candp;
  const int qrow = q0 + w * 16 + r16;
  const int pmask = (r16 & 7) << 4;                // P-strip swizzle mask
  const u16* qph = Qh + ((size_t)(b * T_ + qrow) * HQ_ + hq) * DK_;
  const u16* qpl = Ql + ((size_t)(b * T_ + qrow) * HQ_ + hq) * DK_;
  bf16x8 qh[4], ql[4];
  #pragma unroll
  for (int ks = 0; ks < 4; ++ks) {
    qh[ks] = *(const bf16x8*)(qph + ks * 32 + g * 8);
    ql[ks] = *(const bf16x8*)(qpl + ks * 32 + g * 8);
  }

  float m_run = -1e30f, l_run = 0.f;
  f32x4 oacc[8] = {};

  const int ntile = blockIdx.x + 1;
  for (int it = 0; it < ntile; ++it) {
    const int c0 = it * 64;
    if (c0 >= CANDv && c0 + 63 < q0) continue;   // tile fully masked for all rows
    #pragma unroll
    for (int inst = 0; inst < 4; ++inst) {
      const int p = (inst * 4 + w) * 1024 + lane * 16;
      const int rowK = p >> 8;
      const int scK = ((p >> 4) & 15) ^ (rowK & 7);      // pre-swizzled source chunk
      const size_t gk = ((size_t)(b * T_ + c0 + rowK) * HKV_ + hkv) * DK_ + scK * 8;
      async16(Kth + p, Kh + gk);
      async16(Ktl + p, Kl + gk);
      const int rowV = p >> 7;
      const int scV = ((p >> 4) & 7) ^ (rowV & 7);
      const size_t gv = ((size_t)(b * HKV_ + hkv) * DK_ + rowV) * T_ + c0 + scV * 8;
      async16(Vth + p, VTh + gv);
      async16(Vtl + p, VTl + gv);
    }
    asm volatile("s_waitcnt vmcnt(0)" ::: "memory");
    __syncthreads();

    // S^T[kv][qr] = (Kh+Kl) . (Qh+Ql)^T, dropping lo*lo
    f32x4 stf[4] = {};
    #pragma unroll
    for (int ks = 0; ks < 4; ++ks) {
      #pragma unroll
      for (int kf = 0; kf < 4; ++kf) {
        const int row = kf * 16 + r16;
        const int ch = (ks * 4 + g) ^ (row & 7);
        const int off = row * 256 + ch * 16;
        bf16x8 akh = *(const bf16x8*)(Kth + off);
        bf16x8 akl = *(const bf16x8*)(Ktl + off);
        stf[kf] = mfma16(akh, qh[ks], stf[kf]);
        stf[kf] = mfma16(akh, ql[ks], stf[kf]);
        stf[kf] = mfma16(akl, qh[ks], stf[kf]);
      }
    }
    // mask + online softmax (fp32)
    float pv[16];
    float tmax = -1e30f;
    #pragma unroll
    for (int kf = 0; kf < 4; ++kf)
      #pragma unroll
      for (int j = 0; j < 4; ++j) {
        const int c = c0 + kf * 16 + g * 4 + j;
        float s = stf[kf][j];
        const bool ok = (c <= qrow) && !((qrow >= CANDv) && (c >= CANDv) && (c != qrow));
        s = ok ? s : -1e30f;
        pv[kf * 4 + j] = s;
        tmax = fmaxf(tmax, s);
      }
    tmax = fmaxf(tmax, __shfl_xor(tmax, 16));
    tmax = fmaxf(tmax, __shfl_xor(tmax, 32));
    const float mnew = fmaxf(m_run, tmax);
    const float scal = __expf(m_run - mnew);
    float psum = 0.f;
    #pragma unroll
    for (int i = 0; i < 16; ++i) {
      const float e = (pv[i] > -1e29f) ? __expf(pv[i] - mnew) : 0.f;
      pv[i] = e; psum += e;
    }
    psum += __shfl_xor(psum, 16);
    psum += __shfl_xor(psum, 32);
    l_run = l_run * scal + psum;
    m_run = mnew;
    #pragma unroll
    for (int df = 0; df < 8; ++df)
      #pragma unroll
      for (int j = 0; j < 4; ++j) oacc[df][j] *= scal;
    // write split P[qr][kv] to this wave's LDS strips (swizzled by pmask)
    #pragma unroll
    for (int kf = 0; kf < 4; ++kf) {
      u16 h0 = f2bs(pv[kf * 4 + 0]), h1 = f2bs(pv[kf * 4 + 1]);
      u16 h2 = f2bs(pv[kf * 4 + 2]), h3 = f2bs(pv[kf * 4 + 3]);
      u16 l0 = f2bs(pv[kf * 4 + 0] - bs2f(h0)), l1 = f2bs(pv[kf * 4 + 1] - bs2f(h1));
      u16 l2 = f2bs(pv[kf * 4 + 2] - bs2f(h2)), l3 = f2bs(pv[kf * 4 + 3] - bs2f(h3));
      uint2 ph, pl;
      ph.x = (unsigned)h0 | ((unsigned)h1 << 16); ph.y = (unsigned)h2 | ((unsigned)h3 << 16);
      pl.x = (unsigned)l0 | ((unsigned)l1 << 16); pl.y = (unsigned)l2 | ((unsigned)l3 << 16);
      *(uint2*)(Pth + r16 * 128 + ((kf * 32 + g * 8) ^ pmask)) = ph;
      *(uint2*)(Ptl + r16 * 128 + ((kf * 32 + g * 8) ^ pmask)) = pl;
    }
    // fence: ds_write (uint2) -> ds_read (bf16x8) are TBAA-distinct
    asm volatile("s_waitcnt lgkmcnt(0)" ::: "memory");
    __builtin_amdgcn_sched_barrier(0);
    // O^T[d][qr] += (Vh+Vl)^T . (Ph+Pl)^T, dropping lo*lo
    #pragma unroll
    for (int ks = 0; ks < 2; ++ks) {
      bf16x8 pfh = *(const bf16x8*)(Pth + r16 * 128 + ((ks * 64 + g * 16) ^ pmask));
      bf16x8 pfl = *(const bf16x8*)(Ptl + r16 * 128 + ((ks * 64 + g * 16) ^ pmask));
      #pragma unroll
      for (int df = 0; df < 8; ++df) {
        const int row = df * 16 + r16;
        const int ch = (ks * 4 + g) ^ (row & 7);
        const int off = row * 128 + ch * 16;
        bf16x8 avh = *(const bf16x8*)(Vth + off);
        bf16x8 avl = *(const bf16x8*)(Vtl + off);
        oacc[df] = mfma16(avh, pfh, oacc[df]);
        oacc[df] = mfma16(avh, pfl, oacc[df]);
        oacc[df] = mfma16(avl, pfh, oacc[df]);
      }
    }
    __syncthreads();
  }
  const float inv = 1.f / l_run;
  u16* oph = Ohi + ((size_t)(b * T_ + qrow) * HQ_ + hq) * DK_;
  u16* opl = Olo + ((size_t)(b * T_ + qrow) * HQ_ + hq) * DK_;
  #pragma unroll
  for (int df = 0; df < 8; ++df) {
    float o0 = oacc[df][0] * inv, o1 = oacc[df][1] * inv;
    float o2 = oacc[df][2] * inv, o3 = oacc[df][3] * inv;
    u16 h0 = f2bs(o0), h1 = f2bs(o1), h2 = f2bs(o2), h3 = f2bs(o3);
    u16 l0 = f2bs(o0 - bs2f(h0)), l1 = f2bs(o1 - bs2f(h1));
    u16 l2 = f2bs(o2 - bs2f(h2)), l3 = f2bs(o3 - bs2f(h3));
    uint2 ph, pl;
    ph.x = (unsigned)h0 | ((unsigned)h1 << 16); ph.y = (unsigned)h2 | ((unsigned)h3 << 16);
    pl.x = (unsigned)l0 | ((unsigned)l1 << 16); pl.y = (unsigned)l2 | ((unsigned)l3 << 16);
    *(uint2*)(oph + df * 16 + g * 4) = ph;
    *(uint2*)(opl + df * 16 + g * 4) = pl;
  }
}

// ---------------------------------------------------------------- launch
extern "C" void kernel_launch(void* const* d_in, const int* in_sizes, int n_in,
                              void* d_out, int out_size, void* d_ws, size_t ws_size,
                              hipStream_t stream) {
  (void)in_sizes; (void)n_in; (void)out_size; (void)ws_size;
  const float* x    = (const float*)d_in[0];
  const float* s1   = (const float*)d_in[1];
  const float* s2   = (const float*)d_in[2];
  const float* s3   = (const float*)d_in[3];
  const float* wq   = (const float*)d_in[4];
  const float* wk   = (const float*)d_in[5];
  const float* wv   = (const float*)d_in[6];
  const float* wo   = (const float*)d_in[7];
  const float* wg   = (const float*)d_in[8];
  const float* wvl  = (const float*)d_in[9];
  const float* wout = (const float*)d_in[10];
  const int*   cand = (const int*)d_in[11];

  float* h = (float*)d_out;
  char* ws = (char*)d_ws;
  size_t off = 0;
  auto nxt = [&](size_t bytes) -> char* {
    char* p = ws + off; off += (bytes + 255) & ~(size_t)255; return p;
  };
  // ~133.7 MB total (<= 148.8 MB proven usable in round 4).
  u16* wThi  = (u16*)nxt((size_t)HIDP_ * D_ * 2);   // 22.5 MB
  u16* wTlo  = (u16*)nxt((size_t)HIDP_ * D_ * 2);   // 22.5 MB
  u16* hnhi  = (u16*)nxt((size_t)BT_ * D_ * 2);     //  8.4 MB
  u16* hnlo  = (u16*)nxt((size_t)BT_ * D_ * 2);     //  8.4 MB
  char* U    = nxt((size_t)68 << 20);               // 68 MiB (overlay needs 64 MiB)
  float* ct  = (float*)nxt((size_t)T_ * 64 * 4);
  float* st  = (float*)nxt((size_t)T_ * 64 * 4);
  // attention-phase overlay of U:
  size_t uo = 0;
  auto unxt = [&](size_t bytes) -> char* {
    char* p = U + uo; uo += (bytes + 255) & ~(size_t)255; return p;
  };
  float* qkvf = (float*)unxt((size_t)BT_ * NQKV_ * 4);       // 25.2 MB
  u16* qbhi   = (u16*)unxt((size_t)BT_ * HQ_ * DK_ * 2);
  u16* qblo   = (u16*)unxt((size_t)BT_ * HQ_ * DK_ * 2);
  u16* kbhi   = (u16*)unxt((size_t)BT_ * HKV_ * DK_ * 2);
  u16* kblo   = (u16*)unxt((size_t)BT_ * HKV_ * DK_ * 2);
  u16* vthi   = (u16*)unxt((size_t)BT_ * HKV_ * DK_ * 2);
  u16* vtlo   = (u16*)unxt((size_t)BT_ * HKV_ * DK_ * 2);
  u16* obhi   = (u16*)unxt((size_t)BT_ * HQ_ * DK_ * 2);
  u16* oblo   = (u16*)unxt((size_t)BT_ * HQ_ * DK_ * 2);
  // FFN-phase overlay of U (45.1 MB):
  u16* ghi = (u16*)U;
  u16* glo = (u16*)(U + (size_t)BT_ * HIDP_ * 2);

  copy_f4_k<<<BT_ * D_ / 4 / 256, 256, 0, stream>>>((const float4*)x, (float4*)h, BT_ * D_ / 4);
  rope_tab_k<<<T_ * 64 / 256, 256, 0, stream>>>(ct, st);

  for (int l = 0; l < L_; ++l) {
    const float* wq_l   = wq   + (size_t)l * D_ * (HQ_ * DK_);
    const float* wk_l   = wk   + (size_t)l * D_ * (HKV_ * DK_);
    const float* wv_l   = wv   + (size_t)l * D_ * (HKV_ * DK_);
    const float* wo_l   = wo   + (size_t)l * (HQ_ * DK_) * D_;
    const float* wg_l   = wg   + (size_t)l * D_ * HID_;
    const float* wvl_l  = wvl  + (size_t)l * D_ * HID_;
    const float* wout_l = wout + (size_t)l * HID_ * D_;

    // ---- attention block
    rmsnorm_s<<<BT_, 256, 0, stream>>>(h, s1 + (size_t)l * D_, hnhi, hnlo);
    transpose_split_k<<<dim3(32, 32), 256, 0, stream>>>(wq_l, wThi, wTlo, D_, HQ_ * DK_, D_);
    transpose_split_k<<<dim3(32, 8), 256, 0, stream>>>(wk_l, wThi + (size_t)HQ_ * DK_ * D_,
        wTlo + (size_t)HQ_ * DK_ * D_, D_, HKV_ * DK_, D_);
    transpose_split_k<<<dim3(32, 8), 256, 0, stream>>>(wv_l, wThi + (size_t)VOFF_ * D_,
        wTlo + (size_t)VOFF_ * D_, D_, HKV_ * DK_, D_);
    gemm_bts_k<0><<<dim3(NQKV_ / 128, BT_ / 256), 512, 0, stream>>>(
        hnhi, hnlo, wThi, wTlo, qkvf, nullptr, nullptr, NQKV_, D_);
    rope_split_qkv_k<<<BT_, 256, 0, stream>>>(qkvf, ct, st, qbhi, qblo, kbhi, kblo);
    transpose_v_split_k<<<dim3(T_ / 64, DK_ / 64, B_ * HKV_), 256, 0, stream>>>(qkvf, vthi, vtlo);
    attn_s_k<<<dim3(T_ / 64, HQ_, B_), 256, 0, stream>>>(
        qbhi, qblo, kbhi, kblo, vthi, vtlo, obhi, oblo, cand);
    transpose_split_k<<<dim3(32, 32), 256, 0, stream>>>(wo_l, wThi, wTlo, HQ_ * DK_, D_, D_);
    gemm_bts_k<1><<<dim3(D_ / 128, BT_ / 256), 512, 0, stream>>>(
        obhi, oblo, wThi, wTlo, h, nullptr, nullptr, D_, D_);

    // ---- FFN block
    rmsnorm_s<<<BT_, 256, 0, stream>>>(h, s2 + (size_t)l * D_, hnhi, hnlo);
    transpose_split_k<<<dim3(32, HIDP_ / 64), 256, 0, stream>>>(wg_l, wThi, wTlo, D_, HID_, D_);
    gemm_bts_k<3><<<dim3(HIDP_ / 128, BT_ / 256), 512, 0, stream>>>(
        hnhi, hnlo, wThi, wTlo, nullptr, ghi, glo, HIDP_, D_);
    transpose_split_k<<<dim3(32, HIDP_ / 64), 256, 0, stream>>>(wvl_l, wThi, wTlo, D_, HID_, D_);
    gemm_bts_k<2><<<dim3(HIDP_ / 128, BT_ / 256), 512, 0, stream>>>(
        hnhi, hnlo, wThi, wTlo, nullptr, ghi, glo, HIDP_, D_);
    transpose_split_k<<<dim3(HIDP_ / 64, 32), 256, 0, stream>>>(wout_l, wThi, wTlo, HID_, D_, HIDP_);
    gemm_bts_k<1><<<dim3(D_ / 128, BT_ / 256), 512, 0, stream>>>(
        ghi, glo, wThi, wTlo, h, nullptr, nullptr, D_, HIDP_);
    rmsnorm_f<<<BT_, 256, 0, stream>>>(h, s3 + (size_t)l * D_, h);
  }
}

// Round 22
// 3170.761 us; speedup vs baseline: 1.3588x; 1.3588x over previous
//
#include <hip/hip_runtime.h>
#include <stdint.h>

#define L_ 4
#define B_ 2
#define T_ 1024
#define D_ 2048
#define HQ_ 16
#define HKV_ 4
#define DK_ 128
#define HID_ 5464
#define HIDP_ 5504
#define BT_ (B_*T_)
#define NQKV_ (HQ_*DK_ + 2*HKV_*DK_)   /* 3072 */
#define VOFF_ (HQ_*DK_ + HKV_*DK_)     /* 2560 */

typedef unsigned short u16;
typedef float f32x4 __attribute__((ext_vector_type(4)));
typedef __bf16 bf16x8 __attribute__((ext_vector_type(8)));

__device__ __forceinline__ u16 f2bs(float f) {
  unsigned u = __float_as_uint(f);
  u += 0x7fffu + ((u >> 16) & 1u);
  return (u16)(u >> 16);
}
__device__ __forceinline__ float bs2f(u16 s) {
  return __uint_as_float(((unsigned)s) << 16);
}

// async global->LDS, 16B per lane. LDS dest = first-lane value + lane*16.
__device__ __forceinline__ void async16(void* lds, const void* g) {
  __builtin_amdgcn_global_load_lds(
      (const __attribute__((address_space(1))) unsigned*)(uintptr_t)g,
      (__attribute__((address_space(3))) unsigned*)(unsigned)(uintptr_t)lds,
      16, 0, 0);
}

__device__ __forceinline__ f32x4 mfma16(bf16x8 a, bf16x8 b, f32x4 c) {
  return __builtin_amdgcn_mfma_f32_16x16x32_bf16(a, b, c, 0, 0, 0);
}

// Bijective XCD chunking (m204) + Triton-style GROUP block-order swizzle for L2 reuse.
__device__ __forceinline__ void remap_bid(int& bm, int& bn) {
  const int nbx = gridDim.x, nby = gridDim.y;
  const int nwg = nbx * nby;
  const int lin = blockIdx.y * nbx + blockIdx.x;
  const int q = nwg >> 3, r = nwg & 7;
  const int xcd = lin & 7, rest = lin >> 3;
  const int wgid = (xcd < r ? xcd * (q + 1) : r * (q + 1) + (xcd - r) * q) + rest;
  const int GROUP = 4;
  const int tpg = GROUP * nby;
  const int gid = wgid / tpg;
  const int first = gid * GROUP;
  const int size = (GROUP < nbx - first) ? GROUP : (nbx - first);
  const int rem = wgid - gid * tpg;
  bn = first + rem % size;
  bm = rem / size;
}

// ---------------------------------------------------------------- utility
__global__ void copy_f4_k(const float4* __restrict__ src, float4* __restrict__ dst, int n4) {
  int i = blockIdx.x * blockDim.x + threadIdx.x;
  if (i < n4) dst[i] = src[i];
}

__global__ void rope_tab_k(float* __restrict__ ct, float* __restrict__ st) {
  int idx = blockIdx.x * 256 + threadIdx.x;   // T_*64 total
  int t = idx >> 6, i = idx & 63;
  float inv = expf(-(float)i * (9.210340371976184f / 64.f));  // 10000^(-i/64)
  float fr = (float)t * inv;
  ct[idx] = cosf(fr);
  st[idx] = sinf(fr);
}

// transpose + fp32->(hi,lo) split: out[oi][oj] = in[oj][oi], zero-pad outside [inR][inC]
__global__ __launch_bounds__(256) void transpose_split_k(
    const float* __restrict__ in, u16* __restrict__ outh, u16* __restrict__ outl,
    int inR, int inC, int outC) {
  __shared__ float tile[64][65];
  const int oj0 = blockIdx.x * 64;   // out col = in row
  const int oi0 = blockIdx.y * 64;   // out row = in col
  #pragma unroll
  for (int rep = 0; rep < 16; ++rep) {
    int idx = rep * 256 + threadIdx.x;
    int a = idx >> 6, b = idx & 63;
    int ir = oj0 + a, ic = oi0 + b;
    tile[a][b] = (ir < inR && ic < inC) ? in[(size_t)ir * inC + ic] : 0.f;
  }
  __syncthreads();
  #pragma unroll
  for (int rep = 0; rep < 16; ++rep) {
    int idx = rep * 256 + threadIdx.x;
    int ii = idx >> 6, jj = idx & 63;
    float val = tile[jj][ii];
    u16 hh = f2bs(val);
    const size_t o = (size_t)(oi0 + ii) * outC + oj0 + jj;
    outh[o] = hh;
    outl[o] = f2bs(val - bs2f(hh));
  }
}

// v (strided inside fused qkv, fp32) -> split bf16 vt [B,HKV,DK,T]
__global__ __launch_bounds__(256) void transpose_v_split_k(const float* __restrict__ qkv,
    u16* __restrict__ vth, u16* __restrict__ vtl) {
  __shared__ float tile[64][65];
  const int bz = blockIdx.z;            // b*HKV + hkv
  const int b = bz >> 2, hkv = bz & 3;
  const int t0 = blockIdx.x * 64, d0 = blockIdx.y * 64;
  #pragma unroll
  for (int rep = 0; rep < 16; ++rep) {
    int idx = rep * 256 + threadIdx.x;
    int a = idx >> 6, c = idx & 63;
    tile[a][c] = qkv[(size_t)(b * T_ + t0 + a) * NQKV_ + VOFF_ + hkv * DK_ + d0 + c];
  }
  __syncthreads();
  #pragma unroll
  for (int rep = 0; rep < 16; ++rep) {
    int idx = rep * 256 + threadIdx.x;
    int aa = idx & 63, cc = idx >> 6;
    float val = tile[aa][cc];
    u16 hh = f2bs(val);
    const size_t o = ((size_t)bz * DK_ + d0 + cc) * T_ + t0 + aa;
    vth[o] = hh;
    vtl[o] = f2bs(val - bs2f(hh));
  }
}

// ---------------------------------------------------------------- rmsnorm fp32 -> fp32
__global__ __launch_bounds__(256) void rmsnorm_f(const float* x,
    const float* __restrict__ sc, float* out) {
  const int row = blockIdx.x;
  const float* xr = x + (size_t)row * D_;
  float ss = 0.f;
  #pragma unroll
  for (int it = 0; it < D_ / 1024; ++it) {
    int i = (it * 256 + threadIdx.x) * 4;
    float4 v = *(const float4*)(xr + i);
    ss += v.x * v.x + v.y * v.y + v.z * v.z + v.w * v.w;
  }
  #pragma unroll
  for (int o = 1; o < 64; o <<= 1) ss += __shfl_xor(ss, o);
  __shared__ float red[4];
  if ((threadIdx.x & 63) == 0) red[threadIdx.x >> 6] = ss;
  __syncthreads();
  float tot = red[0] + red[1] + red[2] + red[3];
  float r = rsqrtf(tot * (1.f / D_) + 1e-5f);
  float* orow = out + (size_t)row * D_;
  #pragma unroll
  for (int it = 0; it < D_ / 1024; ++it) {
    int i = (it * 256 + threadIdx.x) * 4;
    float4 v = *(const float4*)(xr + i);
    float4 s4 = *(const float4*)(sc + i);
    float4 o4;
    o4.x = v.x * s4.x * r; o4.y = v.y * s4.y * r;
    o4.z = v.z * s4.z * r; o4.w = v.w * s4.w * r;
    *(float4*)(orow + i) = o4;
  }
}

// ---------------------------------------------------------------- rmsnorm fp32 -> split bf16
__global__ __launch_bounds__(256) void rmsnorm_s(const float* x,
    const float* __restrict__ sc, u16* ohi, u16* olo) {
  const int row = blockIdx.x;
  const float* xr = x + (size_t)row * D_;
  float ss = 0.f;
  #pragma unroll
  for (int it = 0; it < D_ / 1024; ++it) {
    int i = (it * 256 + threadIdx.x) * 4;
    float4 v = *(const float4*)(xr + i);
    ss += v.x * v.x + v.y * v.y + v.z * v.z + v.w * v.w;
  }
  #pragma unroll
  for (int o = 1; o < 64; o <<= 1) ss += __shfl_xor(ss, o);
  __shared__ float red[4];
  if ((threadIdx.x & 63) == 0) red[threadIdx.x >> 6] = ss;
  __syncthreads();
  float tot = red[0] + red[1] + red[2] + red[3];
  float r = rsqrtf(tot * (1.f / D_) + 1e-5f);
  #pragma unroll
  for (int it = 0; it < D_ / 1024; ++it) {
    int i = (it * 256 + threadIdx.x) * 4;
    float4 v = *(const float4*)(xr + i);
    float4 s4 = *(const float4*)(sc + i);
    float o0 = v.x * s4.x * r, o1 = v.y * s4.y * r, o2 = v.z * s4.z * r, o3 = v.w * s4.w * r;
    u16 h0 = f2bs(o0), h1 = f2bs(o1), h2 = f2bs(o2), h3 = f2bs(o3);
    u16 l0 = f2bs(o0 - bs2f(h0)), l1 = f2bs(o1 - bs2f(h1));
    u16 l2 = f2bs(o2 - bs2f(h2)), l3 = f2bs(o3 - bs2f(h3));
    uint2 ph, pl;
    ph.x = (unsigned)h0 | ((unsigned)h1 << 16); ph.y = (unsigned)h2 | ((unsigned)h3 << 16);
    pl.x = (unsigned)l0 | ((unsigned)l1 << 16); pl.y = (unsigned)l2 | ((unsigned)l3 << 16);
    *(uint2*)(ohi + (size_t)row * D_ + i) = ph;
    *(uint2*)(olo + (size_t)row * D_ + i) = pl;
  }
}

// ---------------------------------------------------------------- SPLIT-bf16 MFMA GEMM (R18/R20 config: best)
// 512 threads / 8 waves (4x2 of 32x64), BK=32, DOUBLE-BUFFERED 2x32KB = 64KB LDS
// -> 2 blocks/CU = 4 waves/SIMD (VGPR 52). This is the measured optimum of the
// 2-phase template: BK{32,64}, wave shapes{32x64,64x64}, blocks/CU{1,2,4},
// BM{128,256} all probed and regressed. Counted-vmcnt prefetch (T4):
// stage(kt+1) -> vmcnt(4) -> raw s_barrier -> compute -> lgkmcnt(0) -> raw s_barrier.
// C = (Ahi+Alo) x (Bhi+Blo)^T dropping lo*lo. A[M][K], Bt[N][K].
// Swizzle (rule 21): linear LDS dest, 64B rows, src chunk ^= (row>>1)&3, read same mask.
// MODE 0: Cf = acc ; 1: Cf += acc ; 2: in-place gelu: r=gelu(Chi+Clo)*acc -> Chi/Clo ;
// MODE 3: split acc -> Chi/Clo.
template <int MODE>
__global__ __launch_bounds__(512, 4) void gemm_bts_k(
    const u16* __restrict__ Ahi, const u16* __restrict__ Alo,
    const u16* __restrict__ Bthi, const u16* __restrict__ Btlo,
    float* Cf, u16* Chi, u16* Clo, int N, int K) {
  __shared__ u16 smem[128 * 32 * 4 * 2];      // 64KB: 2 bufs x {Ah|Al|Bh|Bl}, 8KB each
  const int tid = threadIdx.x, w = tid >> 6, lane = tid & 63;
  const int g = lane >> 4, r16 = lane & 15;
  int bm, bn;
  remap_bid(bm, bn);
  const int m0 = bm * 128, n0 = bn * 128;
  const int wr = w >> 1, wc = w & 1;          // 4 x 2 waves, each 32x64
  f32x4 acc[2][4] = {};
  const int nkt = K >> 5;

  const int sp = tid * 16;                    // byte in 8KB tile (512 x 16B)
  const int srow = sp >> 6;                   // 64B rows
  const int ssc = ((sp >> 4) & 3) ^ ((srow >> 1) & 3);
  auto stage = [&](int kt, int buf) {         // 4 async16 per thread
    char* base = (char*)smem + buf * 32768;
    const size_t ga = (size_t)(m0 + srow) * K + (kt << 5) + ssc * 8;
    const size_t gb = (size_t)(n0 + srow) * K + (kt << 5) + ssc * 8;
    async16(base + sp, Ahi + ga);
    async16(base + 8192 + sp, Alo + ga);
    async16(base + 16384 + sp, Bthi + gb);
    async16(base + 24576 + sp, Btlo + gb);
  };

  stage(0, 0);
  for (int kt = 0; kt < nkt; ++kt) {
    const int cur = kt & 1;
    if (kt + 1 < nkt) {
      stage(kt + 1, cur ^ 1);
      asm volatile("s_waitcnt vmcnt(4)" ::: "memory");   // tile kt landed; kt+1 in flight
    } else {
      asm volatile("s_waitcnt vmcnt(0)" ::: "memory");
    }
    __builtin_amdgcn_s_barrier();
    __builtin_amdgcn_sched_barrier(0);
    char* Ash = (char*)smem + cur * 32768;
    char* Asl = Ash + 8192;
    char* Bsh = Ash + 16384;
    char* Bsl = Ash + 24576;
    bf16x8 ah[2], al[2], bh[4], bl[4];
    #pragma unroll
    for (int m = 0; m < 2; ++m) {
      const int row = wr * 32 + m * 16 + r16;
      const int ch = g ^ ((row >> 1) & 3);
      const int off = row * 64 + ch * 16;
      ah[m] = *(const bf16x8*)(Ash + off);
      al[m] = *(const bf16x8*)(Asl + off);
    }
    #pragma unroll
    for (int n = 0; n < 4; ++n) {
      const int row = wc * 64 + n * 16 + r16;
      const int ch = g ^ ((row >> 1) & 3);
      const int off = row * 64 + ch * 16;
      bh[n] = *(const bf16x8*)(Bsh + off);
      bl[n] = *(const bf16x8*)(Bsl + off);
    }
    #pragma unroll
    for (int m = 0; m < 2; ++m)
      #pragma unroll
      for (int n = 0; n < 4; ++n) {
        acc[m][n] = mfma16(ah[m], bh[n], acc[m][n]);
        acc[m][n] = mfma16(ah[m], bl[n], acc[m][n]);
        acc[m][n] = mfma16(al[m], bh[n], acc[m][n]);
      }
    asm volatile("s_waitcnt lgkmcnt(0)" ::: "memory");   // all ds_reads of cur retired
    __builtin_amdgcn_s_barrier();                        // safe to overwrite cur next iter
    __builtin_amdgcn_sched_barrier(0);
  }
  #pragma unroll
  for (int m = 0; m < 2; ++m) {
    const int rbase = m0 + wr * 32 + m * 16 + g * 4;
    #pragma unroll
    for (int n = 0; n < 4; ++n) {
      const int c = n0 + wc * 64 + n * 16 + r16;
      #pragma unroll
      for (int j = 0; j < 4; ++j) {
        const size_t idx = (size_t)(rbase + j) * N + c;
        const float v = acc[m][n][j];
        if constexpr (MODE == 0) {
          Cf[idx] = v;
        } else if constexpr (MODE == 1) {
          Cf[idx] += v;
        } else if constexpr (MODE == 2) {
          const float gv = bs2f(Chi[idx]) + bs2f(Clo[idx]);
          const float ge = 0.5f * gv * (1.f + erff(gv * 0.70710678118654752f));
          const float r = ge * v;
          const u16 rh = f2bs(r);
          Chi[idx] = rh;
          Clo[idx] = f2bs(r - bs2f(rh));
        } else {
          const u16 rh = f2bs(v);
          Chi[idx] = rh;
          Clo[idx] = f2bs(v - bs2f(rh));
        }
      }
    }
  }
}

// ---------------------------------------------------------------- fused rope + q/k split
__global__ __launch_bounds__(256) void rope_split_qkv_k(const float* __restrict__ qkv,
    const float* __restrict__ ct, const float* __restrict__ st,
    u16* __restrict__ qhi, u16* __restrict__ qlo,
    u16* __restrict__ khi, u16* __restrict__ klo) {
  const int row = blockIdx.x;          // b*T + t
  const int t = row & (T_ - 1);
  const float* src = qkv + (size_t)row * NQKV_;
  u16* qh = qhi + (size_t)row * (HQ_ * DK_);
  u16* ql = qlo + (size_t)row * (HQ_ * DK_);
  for (int idx = threadIdx.x; idx < HQ_ * 64; idx += 256) {
    int h = idx >> 6, i = idx & 63;
    float c = ct[t * 64 + i], s = st[t * 64 + i];
    float x1 = src[h * DK_ + i], x2 = src[h * DK_ + i + 64];
    float r1 = x1 * c - x2 * s;
    float r2 = x2 * c + x1 * s;
    u16 h1 = f2bs(r1), h2v = f2bs(r2);
    qh[h * DK_ + i]      = h1;  ql[h * DK_ + i]      = f2bs(r1 - bs2f(h1));
    qh[h * DK_ + i + 64] = h2v; ql[h * DK_ + i + 64] = f2bs(r2 - bs2f(h2v));
  }
  const float* srck = src + HQ_ * DK_;
  u16* kh = khi + (size_t)row * (HKV_ * DK_);
  u16* kl = klo + (size_t)row * (HKV_ * DK_);
  for (int idx = threadIdx.x; idx < HKV_ * 64; idx += 256) {
    int h = idx >> 6, i = idx & 63;
    float c = ct[t * 64 + i], s = st[t * 64 + i];
    float x1 = srck[h * DK_ + i], x2 = srck[h * DK_ + i + 64];
    float r1 = x1 * c - x2 * s;
    float r2 = x2 * c + x1 * s;
    u16 h1 = f2bs(r1), h2v = f2bs(r2);
    kh[h * DK_ + i]      = h1;  kl[h * DK_ + i]      = f2bs(r1 - bs2f(h1));
    kh[h * DK_ + i + 64] = h2v; kl[h * DK_ + i + 64] = f2bs(r2 - bs2f(h2v));
  }
}

// ---------------------------------------------------------------- SPLIT-bf16 MFMA flash attention
__global__ __launch_bounds__(256) void attn_s_k(
    const u16* __restrict__ Qh, const u16* __restrict__ Ql,
    const u16* __restrict__ Kh, const u16* __restrict__ Kl,
    const u16* __restrict__ VTh, const u16* __restrict__ VTl,
    u16* __restrict__ Ohi, u16* __restrict__ Olo, const int* __restrict__ candp) {
  __shared__ u16 sm[40960];                 // 80 KB
  char* Kth = (char*)sm;                    // 64 kv x 256B
  char* Ktl = (char*)sm + 16384;
  char* Vth = (char*)sm + 32768;            // 128 d x 128B
  char* Vtl = (char*)sm + 49152;
  const int b = blockIdx.z, hq = blockIdx.y, q0 = blockIdx.x * 64;
  const int hkv = hq >> 2;
  const int tid = threadIdx.x, w = tid >> 6, lane = tid & 63;
  const int g = lane >> 4, r16 = lane & 15;
  char* Pth = (char*)sm + 65536 + w * 2048;        // 4 waves x 2KB
  char* Ptl = (char*)sm + 65536 + 8192 + w * 2048; // 4 waves x 2KB (ends at 81920)
  const int CANDv = *candp;
  const int qrow = q0 + w * 16 + r16;
  const int pmask = (r16 & 7) << 4;                // P-strip swizzle mask
  const u16* qph = Qh + ((size_t)(b * T_ + qrow) * HQ_ + hq) * DK_;
  const u16* qpl = Ql + ((size_t)(b * T_ + qrow) * HQ_ + hq) * DK_;
  bf16x8 qh[4], ql[4];
  #pragma unroll
  for (int ks = 0; ks < 4; ++ks) {
    qh[ks] = *(const bf16x8*)(qph + ks * 32 + g * 8);
    ql[ks] = *(const bf16x8*)(qpl + ks * 32 + g * 8);
  }

  float m_run = -1e30f, l_run = 0.f;
  f32x4 oacc[8] = {};

  const int ntile = blockIdx.x + 1;
  for (int it = 0; it < ntile; ++it) {
    const int c0 = it * 64;
    if (c0 >= CANDv && c0 + 63 < q0) continue;   // tile fully masked for all rows
    #pragma unroll
    for (int inst = 0; inst < 4; ++inst) {
      const int p = (inst * 4 + w) * 1024 + lane * 16;
      const int rowK = p >> 8;
      const int scK = ((p >> 4) & 15) ^ (rowK & 7);      // pre-swizzled source chunk
      const size_t gk = ((size_t)(b * T_ + c0 + rowK) * HKV_ + hkv) * DK_ + scK * 8;
      async16(Kth + p, Kh + gk);
      async16(Ktl + p, Kl + gk);
      const int rowV = p >> 7;
      const int scV = ((p >> 4) & 7) ^ (rowV & 7);
      const size_t gv = ((size_t)(b * HKV_ + hkv) * DK_ + rowV) * T_ + c0 + scV * 8;
      async16(Vth + p, VTh + gv);
      async16(Vtl + p, VTl + gv);
    }
    asm volatile("s_waitcnt vmcnt(0)" ::: "memory");
    __syncthreads();

    // S^T[kv][qr] = (Kh+Kl) . (Qh+Ql)^T, dropping lo*lo
    f32x4 stf[4] = {};
    #pragma unroll
    for (int ks = 0; ks < 4; ++ks) {
      #pragma unroll
      for (int kf = 0; kf < 4; ++kf) {
        const int row = kf * 16 + r16;
        const int ch = (ks * 4 + g) ^ (row & 7);
        const int off = row * 256 + ch * 16;
        bf16x8 akh = *(const bf16x8*)(Kth + off);
        bf16x8 akl = *(const bf16x8*)(Ktl + off);
        stf[kf] = mfma16(akh, qh[ks], stf[kf]);
        stf[kf] = mfma16(akh, ql[ks], stf[kf]);
        stf[kf] = mfma16(akl, qh[ks], stf[kf]);
      }
    }
    // mask + online softmax (fp32)
    float pv[16];
    float tmax = -1e30f;
    #pragma unroll
    for (int kf = 0; kf < 4; ++kf)
      #pragma unroll
      for (int j = 0; j < 4; ++j) {
        const int c = c0 + kf * 16 + g * 4 + j;
        float s = stf[kf][j];
        const bool ok = (c <= qrow) && !((qrow >= CANDv) && (c >= CANDv) && (c != qrow));
        s = ok ? s : -1e30f;
        pv[kf * 4 + j] = s;
        tmax = fmaxf(tmax, s);
      }
    tmax = fmaxf(tmax, __shfl_xor(tmax, 16));
    tmax = fmaxf(tmax, __shfl_xor(tmax, 32));
    const float mnew = fmaxf(m_run, tmax);
    const float scal = __expf(m_run - mnew);
    float psum = 0.f;
    #pragma unroll
    for (int i = 0; i < 16; ++i) {
      const float e = (pv[i] > -1e29f) ? __expf(pv[i] - mnew) : 0.f;
      pv[i] = e; psum += e;
    }
    psum += __shfl_xor(psum, 16);
    psum += __shfl_xor(psum, 32);
    l_run = l_run * scal + psum;
    m_run = mnew;
    #pragma unroll
    for (int df = 0; df < 8; ++df)
      #pragma unroll
      for (int j = 0; j < 4; ++j) oacc[df][j] *= scal;
    // write split P[qr][kv] to this wave's LDS strips (swizzled by pmask)
    #pragma unroll
    for (int kf = 0; kf < 4; ++kf) {
      u16 h0 = f2bs(pv[kf * 4 + 0]), h1 = f2bs(pv[kf * 4 + 1]);
      u16 h2 = f2bs(pv[kf * 4 + 2]), h3 = f2bs(pv[kf * 4 + 3]);
      u16 l0 = f2bs(pv[kf * 4 + 0] - bs2f(h0)), l1 = f2bs(pv[kf * 4 + 1] - bs2f(h1));
      u16 l2 = f2bs(pv[kf * 4 + 2] - bs2f(h2)), l3 = f2bs(pv[kf * 4 + 3] - bs2f(h3));
      uint2 ph, pl;
      ph.x = (unsigned)h0 | ((unsigned)h1 << 16); ph.y = (unsigned)h2 | ((unsigned)h3 << 16);
      pl.x = (unsigned)l0 | ((unsigned)l1 << 16); pl.y = (unsigned)l2 | ((unsigned)l3 << 16);
      *(uint2*)(Pth + r16 * 128 + ((kf * 32 + g * 8) ^ pmask)) = ph;
      *(uint2*)(Ptl + r16 * 128 + ((kf * 32 + g * 8) ^ pmask)) = pl;
    }
    // fence: ds_write (uint2) -> ds_read (bf16x8) are TBAA-distinct
    asm volatile("s_waitcnt lgkmcnt(0)" ::: "memory");
    __builtin_amdgcn_sched_barrier(0);
    // O^T[d][qr] += (Vh+Vl)^T . (Ph+Pl)^T, dropping lo*lo
    #pragma unroll
    for (int ks = 0; ks < 2; ++ks) {
      bf16x8 pfh = *(const bf16x8*)(Pth + r16 * 128 + ((ks * 64 + g * 16) ^ pmask));
      bf16x8 pfl = *(const bf16x8*)(Ptl + r16 * 128 + ((ks * 64 + g * 16) ^ pmask));
      #pragma unroll
      for (int df = 0; df < 8; ++df) {
        const int row = df * 16 + r16;
        const int ch = (ks * 4 + g) ^ (row & 7);
        const int off = row * 128 + ch * 16;
        bf16x8 avh = *(const bf16x8*)(Vth + off);
        bf16x8 avl = *(const bf16x8*)(Vtl + off);
        oacc[df] = mfma16(avh, pfh, oacc[df]);
        oacc[df] = mfma16(avh, pfl, oacc[df]);
        oacc[df] = mfma16(avl, pfh, oacc[df]);
      }
    }
    __syncthreads();
  }
  const float inv = 1.f / l_run;
  u16* oph = Ohi + ((size_t)(b * T_ + qrow) * HQ_ + hq) * DK_;
  u16* opl = Olo + ((size_t)(b * T_ + qrow) * HQ_ + hq) * DK_;
  #pragma unroll
  for (int df = 0; df < 8; ++df) {
    float o0 = oacc[df][0] * inv, o1 = oacc[df][1] * inv;
    float o2 = oacc[df][2] * inv, o3 = oacc[df][3] * inv;
    u16 h0 = f2bs(o0), h1 = f2bs(o1), h2 = f2bs(o2), h3 = f2bs(o3);
    u16 l0 = f2bs(o0 - bs2f(h0)), l1 = f2bs(o1 - bs2f(h1));
    u16 l2 = f2bs(o2 - bs2f(h2)), l3 = f2bs(o3 - bs2f(h3));
    uint2 ph, pl;
    ph.x = (unsigned)h0 | ((unsigned)h1 << 16); ph.y = (unsigned)h2 | ((unsigned)h3 << 16);
    pl.x = (unsigned)l0 | ((unsigned)l1 << 16); pl.y = (unsigned)l2 | ((unsigned)l3 << 16);
    *(uint2*)(oph + df * 16 + g * 4) = ph;
    *(uint2*)(opl + df * 16 + g * 4) = pl;
  }
}

// ---------------------------------------------------------------- launch
extern "C" void kernel_launch(void* const* d_in, const int* in_sizes, int n_in,
                              void* d_out, int out_size, void* d_ws, size_t ws_size,
                              hipStream_t stream) {
  (void)in_sizes; (void)n_in; (void)out_size; (void)ws_size;
  const float* x    = (const float*)d_in[0];
  const float* s1   = (const float*)d_in[1];
  const float* s2   = (const float*)d_in[2];
  const float* s3   = (const float*)d_in[3];
  const float* wq   = (const float*)d_in[4];
  const float* wk   = (const float*)d_in[5];
  const float* wv   = (const float*)d_in[6];
  const float* wo   = (const float*)d_in[7];
  const float* wg   = (const float*)d_in[8];
  const float* wvl  = (const float*)d_in[9];
  const float* wout = (const float*)d_in[10];
  const int*   cand = (const int*)d_in[11];

  float* h = (float*)d_out;
  char* ws = (char*)d_ws;
  size_t off = 0;
  auto nxt = [&](size_t bytes) -> char* {
    char* p = ws + off; off += (bytes + 255) & ~(size_t)255; return p;
  };
  // ~133.7 MB total (<= 148.8 MB proven usable in round 4).
  u16* wThi  = (u16*)nxt((size_t)HIDP_ * D_ * 2);   // 22.5 MB
  u16* wTlo  = (u16*)nxt((size_t)HIDP_ * D_ * 2);   // 22.5 MB
  u16* hnhi  = (u16*)nxt((size_t)BT_ * D_ * 2);     //  8.4 MB
  u16* hnlo  = (u16*)nxt((size_t)BT_ * D_ * 2);     //  8.4 MB
  char* U    = nxt((size_t)68 << 20);               // 68 MiB (overlay needs 64 MiB)
  float* ct  = (float*)nxt((size_t)T_ * 64 * 4);
  float* st  = (float*)nxt((size_t)T_ * 64 * 4);
  // attention-phase overlay of U:
  size_t uo = 0;
  auto unxt = [&](size_t bytes) -> char* {
    char* p = U + uo; uo += (bytes + 255) & ~(size_t)255; return p;
  };
  float* qkvf = (float*)unxt((size_t)BT_ * NQKV_ * 4);       // 25.2 MB
  u16* qbhi   = (u16*)unxt((size_t)BT_ * HQ_ * DK_ * 2);
  u16* qblo   = (u16*)unxt((size_t)BT_ * HQ_ * DK_ * 2);
  u16* kbhi   = (u16*)unxt((size_t)BT_ * HKV_ * DK_ * 2);
  u16* kblo   = (u16*)unxt((size_t)BT_ * HKV_ * DK_ * 2);
  u16* vthi   = (u16*)unxt((size_t)BT_ * HKV_ * DK_ * 2);
  u16* vtlo   = (u16*)unxt((size_t)BT_ * HKV_ * DK_ * 2);
  u16* obhi   = (u16*)unxt((size_t)BT_ * HQ_ * DK_ * 2);
  u16* oblo   = (u16*)unxt((size_t)BT_ * HQ_ * DK_ * 2);
  // FFN-phase overlay of U (45.1 MB):
  u16* ghi = (u16*)U;
  u16* glo = (u16*)(U + (size_t)BT_ * HIDP_ * 2);

  copy_f4_k<<<BT_ * D_ / 4 / 256, 256, 0, stream>>>((const float4*)x, (float4*)h, BT_ * D_ / 4);
  rope_tab_k<<<T_ * 64 / 256, 256, 0, stream>>>(ct, st);

  for (int l = 0; l < L_; ++l) {
    const float* wq_l   = wq   + (size_t)l * D_ * (HQ_ * DK_);
    const float* wk_l   = wk   + (size_t)l * D_ * (HKV_ * DK_);
    const float* wv_l   = wv   + (size_t)l * D_ * (HKV_ * DK_);
    const float* wo_l   = wo   + (size_t)l * (HQ_ * DK_) * D_;
    const float* wg_l   = wg   + (size_t)l * D_ * HID_;
    const float* wvl_l  = wvl  + (size_t)l * D_ * HID_;
    const float* wout_l = wout + (size_t)l * HID_ * D_;

    // ---- attention block
    rmsnorm_s<<<BT_, 256, 0, stream>>>(h, s1 + (size_t)l * D_, hnhi, hnlo);
    transpose_split_k<<<dim3(32, 32), 256, 0, stream>>>(wq_l, wThi, wTlo, D_, HQ_ * DK_, D_);
    transpose_split_k<<<dim3(32, 8), 256, 0, stream>>>(wk_l, wThi + (size_t)HQ_ * DK_ * D_,
        wTlo + (size_t)HQ_ * DK_ * D_, D_, HKV_ * DK_, D_);
    transpose_split_k<<<dim3(32, 8), 256, 0, stream>>>(wv_l, wThi + (size_t)VOFF_ * D_,
        wTlo + (size_t)VOFF_ * D_, D_, HKV_ * DK_, D_);
    gemm_bts_k<0><<<dim3(NQKV_ / 128, BT_ / 128), 512, 0, stream>>>(
        hnhi, hnlo, wThi, wTlo, qkvf, nullptr, nullptr, NQKV_, D_);
    rope_split_qkv_k<<<BT_, 256, 0, stream>>>(qkvf, ct, st, qbhi, qblo, kbhi, kblo);
    transpose_v_split_k<<<dim3(T_ / 64, DK_ / 64, B_ * HKV_), 256, 0, stream>>>(qkvf, vthi, vtlo);
    attn_s_k<<<dim3(T_ / 64, HQ_, B_), 256, 0, stream>>>(
        qbhi, qblo, kbhi, kblo, vthi, vtlo, obhi, oblo, cand);
    transpose_split_k<<<dim3(32, 32), 256, 0, stream>>>(wo_l, wThi, wTlo, HQ_ * DK_, D_, D_);
    gemm_bts_k<1><<<dim3(D_ / 128, BT_ / 128), 512, 0, stream>>>(
        obhi, oblo, wThi, wTlo, h, nullptr, nullptr, D_, D_);

    // ---- FFN block
    rmsnorm_s<<<BT_, 256, 0, stream>>>(h, s2 + (size_t)l * D_, hnhi, hnlo);
    transpose_split_k<<<dim3(32, HIDP_ / 64), 256, 0, stream>>>(wg_l, wThi, wTlo, D_, HID_, D_);
    gemm_bts_k<3><<<dim3(HIDP_ / 128, BT_ / 128), 512, 0, stream>>>(
        hnhi, hnlo, wThi, wTlo, nullptr, ghi, glo, HIDP_, D_);
    transpose_split_k<<<dim3(32, HIDP_ / 64), 256, 0, stream>>>(wvl_l, wThi, wTlo, D_, HID_, D_);
    gemm_bts_k<2><<<dim3(HIDP_ / 128, BT_ / 128), 512, 0, stream>>>(
        hnhi, hnlo, wThi, wTlo, nullptr, ghi, glo, HIDP_, D_);
    transpose_split_k<<<dim3(HIDP_ / 64, 32), 256, 0, stream>>>(wout_l, wThi, wTlo, HID_, D_, HIDP_);
    gemm_bts_k<1><<<dim3(D_ / 128, BT_ / 128), 512, 0, stream>>>(
        ghi, glo, wThi, wTlo, h, nullptr, nullptr, D_, HIDP_);
    rmsnorm_f<<<BT_, 256, 0, stream>>>(h, s3 + (size_t)l * D_, h);
  }
}